// Round 16
// baseline (2546.165 us; speedup 1.0000x reference)
//
#include <hip/hip_runtime.h>
#include <hip/hip_bf16.h>
#include <math.h>

#define D_MODEL 256
#define NUM_SLOTS 128
#define RANK 32
#define N_STEPS 6
#define VOCAB 32000
#define SEQ 512
#define BATCH 8
#define NTOK (BATCH*SEQ)
#define LN_EPS 1e-5f
#define SM_SCALE 0.0625f
#define IGROUPS 8

// convert block distribution across the four front dispatches
#define CB_A 0
#define NC_A 15360
#define CB_B (CB_A + NC_A)
#define NC_B 11776
#define CB_C (CB_B + NC_B)
#define NC_C 19200
#define CB_D (CB_C + NC_C)
#define NC_D 19200

typedef __attribute__((ext_vector_type(8))) short bf16x8;
typedef __attribute__((ext_vector_type(8))) _Float16 f16x8;
typedef __attribute__((ext_vector_type(4))) float f32x4;

#define GLD_LDS16(g, l) __builtin_amdgcn_global_load_lds( \
    (const __attribute__((address_space(1))) unsigned int*)(g), \
    (__attribute__((address_space(3))) unsigned int*)(l), 16, 0, 0)

__device__ inline unsigned pk2(float a, float b) {
    auto v = __builtin_amdgcn_cvt_pkrtz(a, b);
    union { decltype(v) x; unsigned u; } c;
    c.x = v;
    return c.u;
}
__device__ inline unsigned short f2h(float x) {
    union { _Float16 h; unsigned short u; } c;
    c.h = (_Float16)x;
    return c.u;
}

// ---- convert device body (frozen logic) ----
__device__ __forceinline__ void dev_convert(int cb, int t, float* ldsAll,
        const float* __restrict__ Ws, const float* __restrict__ Wt,
        unsigned short* __restrict__ WF) {
    int z = cb >> 14, i = (cb >> 7) & 127, j = cb & 127;
    int w = t >> 6, l = t & 63;
    float* lw = &ldsAll[w*1056];
    size_t sBase = ((size_t)i*128 + j)*8192;
    size_t pOut = ((size_t)j*128 + i)*16384;
    int g = l >> 4, c = l & 15;
    if (z < 2) {
        int ks = z*4 + w;
        const float4* s4 = (const float4*)(Ws + sBase) + ks*256;
        #pragma unroll
        for (int q = 0; q < 4; ++q) {
            int idx = q*64 + l;
            float4 v = s4[idx];
            *(float4*)&lw[(idx>>3)*33 + 4*(idx&7)] = v;
        }
        asm volatile("s_waitcnt lgkmcnt(0)" ::: "memory");
        bool diag = (i == j);
        #pragma unroll
        for (int mt = 0; mt < 2; ++mt) {
            union { f16x8 v; } o;
            #pragma unroll
            for (int e = 0; e < 8; ++e) {
                float f = diag ? 0.f : lw[(g*8 + e)*33 + mt*16 + c];
                o.v[e] = (_Float16)f;
            }
            *(f16x8*)(WF + pOut + (size_t)((ks*2 + mt)*64 + l)*8) = o.v;
        }
    } else {
        int p0 = (z - 2)*8 + w*2;
        const float4* s4 = (const float4*)(Wt + sBase);
        #pragma unroll
        for (int q = 0; q < 4; ++q) {
            int idx = q*64 + l;
            int r = idx >> 3, c8 = idx & 7;
            float4 v = s4[r*64 + p0*4 + c8];
            *(float4*)&lw[r*33 + 4*c8] = v;
        }
        asm volatile("s_waitcnt lgkmcnt(0)" ::: "memory");
        #pragma unroll
        for (int dn = 0; dn < 2; ++dn) {
            int nt = p0 + dn;
            union { f16x8 v; } o;
            #pragma unroll
            for (int e = 0; e < 8; ++e)
                o.v[e] = (_Float16)lw[(g*8 + e)*33 + dn*16 + c];
            *(f16x8*)(WF + pOut + 8192 + (size_t)(nt*64 + l)*8) = o.v;
        }
    }
}

// ---- front A: gemm3e (embed-fused Qin/Vin/Qout projections) + convert ----
__global__ __launch_bounds__(256) void k_front_a(const int* __restrict__ ids,
        const float* __restrict__ tok, const float* __restrict__ pos,
        const float* __restrict__ B0, const float* __restrict__ B1,
        const float* __restrict__ B2, float* __restrict__ C0,
        float* __restrict__ C1, float* __restrict__ C2,
        const float* __restrict__ Ws, const float* __restrict__ Wt,
        unsigned short* __restrict__ WF, unsigned* __restrict__ ticket) {
    __shared__ float smem[4352];
    int bid = blockIdx.x;
    int t = threadIdx.x;
    if (bid >= 768) { dev_convert(CB_A + bid - 768, t, smem, Ws, Wt, WF); return; }
    if (bid == 0 && t < NUM_SLOTS) ticket[t] = 0u;   // init LN tickets
    const int K = D_MODEL, N = D_MODEL;
    int bx = bid & 63, byz = bid >> 6;
    int by = byz & 3, bz = byz >> 2;
    const float* B = bz == 0 ? B0 : (bz == 1 ? B1 : B2);
    float* C = bz == 0 ? C0 : (bz == 1 ? C1 : C2);
    float* As = smem;
    float* Bs = smem + 2048;
    int* sid = (int*)(smem + 4096);
    int bm = bx * 64, bn = by * 64;
    if (t < 64) sid[t] = ids[bm + t];
    __syncthreads();
    int tm = (t & 15) * 4, tn = (t >> 4) * 4;
    float acc[4][4] = {};
    for (int k0 = 0; k0 < K; k0 += 32) {
        #pragma unroll
        for (int r = 0; r < 8; ++r) {
            int idx = r*256 + t;
            int m = idx >> 5, k = idx & 31;
            int gm = bm + m;
            As[k*64 + m] = tok[(size_t)sid[m]*K + k0 + k] + pos[(gm & (SEQ-1))*K + k0 + k];
        }
        #pragma unroll
        for (int r = 0; r < 8; ++r) {
            int idx = r*256 + t;
            int n = idx >> 5, k = idx & 31;
            Bs[k*64 + n] = B[(size_t)(bn+n)*K + k0 + k];
        }
        __syncthreads();
        #pragma unroll
        for (int k = 0; k < 32; ++k) {
            float4 a4 = *(const float4*)&As[k*64 + tm];
            float4 b4 = *(const float4*)&Bs[k*64 + tn];
            float a[4] = {a4.x,a4.y,a4.z,a4.w};
            float b[4] = {b4.x,b4.y,b4.z,b4.w};
            #pragma unroll
            for (int i = 0; i < 4; ++i)
                #pragma unroll
                for (int jj = 0; jj < 4; ++jj)
                    acc[i][jj] += a[i]*b[jj];
        }
        __syncthreads();
    }
    #pragma unroll
    for (int i = 0; i < 4; ++i) {
        float4 v = make_float4(acc[i][0],acc[i][1],acc[i][2],acc[i][3]);
        *(float4*)&C[(size_t)(bm+tm+i)*N + bn+tn] = v;
    }
}

// ---- front B: Ksl projection + W_out fp16 split + convert ----
__global__ __launch_bounds__(256) void k_front_b(const float* __restrict__ Hin,
        const float* __restrict__ Wk_sl, float* __restrict__ Ksl,
        const float* __restrict__ Wop, unsigned short* __restrict__ Wf16,
        const float* __restrict__ Ws, const float* __restrict__ Wt,
        unsigned short* __restrict__ WF) {
    __shared__ float smem[4352];
    int bid = blockIdx.x;
    int t = threadIdx.x;
    if (bid >= 8008) { dev_convert(CB_B + bid - 8008, t, smem, Ws, Wt, WF); return; }
    if (bid >= 8) {
        int i = (bid - 8)*256 + t;
        float4 v = ((const float4*)Wop)[i];
        ushort4 h;
        h.x = f2h(v.x); h.y = f2h(v.y); h.z = f2h(v.z); h.w = f2h(v.w);
        ((ushort4*)Wf16)[i] = h;
        return;
    }
    const int K = D_MODEL, N = D_MODEL;
    int bx = bid & 1, by = bid >> 1;
    float* As = smem;
    float* Bs = smem + 2048;
    int bm = bx * 64, bn = by * 64;
    int tm = (t & 15) * 4, tn = (t >> 4) * 4;
    float acc[4][4] = {};
    for (int k0 = 0; k0 < K; k0 += 32) {
        #pragma unroll
        for (int r = 0; r < 8; ++r) {
            int idx = r*256 + t;
            int m = idx >> 5, k = idx & 31;
            As[k*64 + m] = Hin[(size_t)(bm+m)*K + k0 + k];
        }
        #pragma unroll
        for (int r = 0; r < 8; ++r) {
            int idx = r*256 + t;
            int n = idx >> 5, k = idx & 31;
            Bs[k*64 + n] = Wk_sl[(size_t)(bn+n)*K + k0 + k];
        }
        __syncthreads();
        #pragma unroll
        for (int k = 0; k < 32; ++k) {
            float4 a4 = *(const float4*)&As[k*64 + tm];
            float4 b4 = *(const float4*)&Bs[k*64 + tn];
            float a[4] = {a4.x,a4.y,a4.z,a4.w};
            float b[4] = {b4.x,b4.y,b4.z,b4.w};
            #pragma unroll
            for (int i = 0; i < 4; ++i)
                #pragma unroll
                for (int jj = 0; jj < 4; ++jj)
                    acc[i][jj] += a[i]*b[jj];
        }
        __syncthreads();
    }
    #pragma unroll
    for (int i = 0; i < 4; ++i) {
        float4 v = make_float4(acc[i][0],acc[i][1],acc[i][2],acc[i][3]);
        *(float4*)&Ksl[(size_t)(bm+tm+i)*N + bn+tn] = v;
    }
}

// ---- front C: compress attention (scores+softmax+mask) + convert ----
__global__ __launch_bounds__(256) void k_front_c(const float* __restrict__ Qin,
        const float* __restrict__ Ksl, const int* __restrict__ mask,
        float* __restrict__ A,
        const float* __restrict__ Ws, const float* __restrict__ Wt,
        unsigned short* __restrict__ WF) {
    __shared__ float smem[4352];
    int bid = blockIdx.x;
    int t = threadIdx.x;
    if (bid >= NTOK) { dev_convert(CB_C + bid - NTOK, t, smem, Ws, Wt, WF); return; }
    int bl = bid;
    float* q   = smem;
    float* prt = smem + 256;
    float* red = smem + 512;
    q[t] = Qin[(size_t)bl*D_MODEL + t];
    __syncthreads();
    int s = t & 127, hf = t >> 7;
    const float* kr = Ksl + (size_t)s*D_MODEL + hf*128;
    float accp = 0.f;
    #pragma unroll 8
    for (int d = 0; d < 128; ++d) accp += q[hf*128 + d]*kr[d];
    prt[hf*128 + s] = accp;
    __syncthreads();
    float v = 0.f;
    if (t < 128) { v = (prt[t] + prt[128 + t]) * SM_SCALE; red[t] = v; }
    __syncthreads();
    for (int o = 64; o > 0; o >>= 1) { if (t < o) red[t] = fmaxf(red[t], red[t+o]); __syncthreads(); }
    float mx = red[0]; __syncthreads();
    float e = 0.f;
    if (t < 128) { e = expf(v - mx); red[t] = e; }
    __syncthreads();
    for (int o = 64; o > 0; o >>= 1) { if (t < o) red[t] += red[t+o]; __syncthreads(); }
    float sum = red[0];
    if (t < 128) {
        float m = (float)mask[bl];
        A[(size_t)bl*NUM_SLOTS + t] = e / sum * m;
    }
}

// ---- front D: slot aggregation (IR, colsum fused) + convert ----
__global__ __launch_bounds__(256) void k_front_d(const float* __restrict__ A,
        const float* __restrict__ V, const float* __restrict__ H,
        float* __restrict__ Hs, unsigned short* __restrict__ Hs16,
        const float* __restrict__ Ws, const float* __restrict__ Wt,
        unsigned short* __restrict__ WF) {
    __shared__ float smem[4352];
    int bid = blockIdx.x;
    int t = threadIdx.x;
    if (bid >= BATCH*NUM_SLOTS) { dev_convert(CB_D + bid - BATCH*NUM_SLOTS, t, smem, Ws, Wt, WF); return; }
    int bs = bid; int b = bs >> 7; int s = bs & 127;
    int d = t;
    const float* Ab = A + (size_t)b*SEQ*NUM_SLOTS + s;
    const float* Vb = V + (size_t)b*SEQ*D_MODEL + d;
    float a0 = 0.f, a1 = 0.f, a2 = 0.f, a3 = 0.f;
    float s0 = 0.f, s1 = 0.f, s2 = 0.f, s3 = 0.f;
    for (int l = 0; l < SEQ; l += 4) {
        float w0 = Ab[(size_t)(l+0)*NUM_SLOTS];
        float w1 = Ab[(size_t)(l+1)*NUM_SLOTS];
        float w2 = Ab[(size_t)(l+2)*NUM_SLOTS];
        float w3 = Ab[(size_t)(l+3)*NUM_SLOTS];
        a0 += w0 * Vb[(size_t)(l+0)*D_MODEL];
        a1 += w1 * Vb[(size_t)(l+1)*D_MODEL];
        a2 += w2 * Vb[(size_t)(l+2)*D_MODEL];
        a3 += w3 * Vb[(size_t)(l+3)*D_MODEL];
        s0 += w0; s1 += w1; s2 += w2; s3 += w3;
    }
    float asum = (s0+s1) + (s2+s3) + 1e-8f;
    float acc = (a0+a1) + (a2+a3);
    float v = H[s*D_MODEL + d] + acc / asum;
    Hs[(size_t)bs*D_MODEL + d] = v;
    Hs16[(size_t)bs*D_MODEL + d] = f2h(v);
}

// logits GEMM: 1-pass fp16 MFMA, global_load_lds staging (frozen)
__global__ __launch_bounds__(256) void k_logits(
        const unsigned short* __restrict__ Ahg,
        const unsigned short* __restrict__ Bhg, float* __restrict__ C) {
    __shared__ unsigned short lds[2*8192];
    int bm = blockIdx.x * 128, bn = blockIdx.y * 128;
    int t = threadIdx.x;
    int w = t >> 6, l = t & 63;
    int wr = w >> 1, wc = w & 1;
    int lr = l & 15, lk = l >> 4;
    f32x4 acc[4][4];
    #pragma unroll
    for (int mi = 0; mi < 4; ++mi)
        #pragma unroll
        for (int ni = 0; ni < 4; ++ni)
            acc[mi][ni] = (f32x4){0.f,0.f,0.f,0.f};

    for (int kc = 0; kc < 4; ++kc) {
        if (kc) __syncthreads();
        #pragma unroll
        for (int i = 0; i < 4; ++i) {
            int c = t + i*256;
            int row = c >> 3, c8 = c & 7;
            size_t ga = (size_t)(bm+row)*256 + kc*64 + c8*8;
            size_t gb = (size_t)(bn+row)*256 + kc*64 + c8*8;
            GLD_LDS16(Ahg + ga, &lds[c*8]);
            GLD_LDS16(Bhg + gb, &lds[8192 + c*8]);
        }
        __syncthreads();
        #pragma unroll
        for (int s = 0; s < 2; ++s) {
            f16x8 ah[4], bh[4];
            #pragma unroll
            for (int mi = 0; mi < 4; ++mi) {
                int off = (wr*64 + mi*16 + lr)*64 + s*32 + lk*8;
                ah[mi] = *(const f16x8*)&lds[off];
            }
            #pragma unroll
            for (int ni = 0; ni < 4; ++ni) {
                int off = (wc*64 + ni*16 + lr)*64 + s*32 + lk*8;
                bh[ni] = *(const f16x8*)&lds[8192 + off];
            }
            #pragma unroll
            for (int mi = 0; mi < 4; ++mi)
                #pragma unroll
                for (int ni = 0; ni < 4; ++ni)
                    acc[mi][ni] = __builtin_amdgcn_mfma_f32_16x16x32_f16(ah[mi], bh[ni], acc[mi][ni], 0, 0, 0);
        }
    }
    #pragma unroll
    for (int mi = 0; mi < 4; ++mi)
        #pragma unroll
        for (int ni = 0; ni < 4; ++ni) {
            int col = bn + wc*64 + ni*16 + lr;
            #pragma unroll
            for (int r = 0; r < 4; ++r) {
                int row = bm + wr*64 + mi*16 + lk*4 + r;
                C[(size_t)row*VOCAB + col] = acc[mi][ni][r];
            }
        }
}

// ---- MFMA slot-pair kernel + fused LN tail (race-free ping-pong) ----
// Reads h16in (state of step st); the 8th-arriving block per slot j performs
// LN and writes h16out (NEXT step's buffer) + Hst. No within-dispatch reader
// of h16out -> no race. Ticket reset via device-scope atomicExch.
__global__ __launch_bounds__(256, 4) void k_pairs_mfma(const unsigned short* __restrict__ h16in,
        const unsigned short* __restrict__ WF, float* __restrict__ part,
        float* __restrict__ Hst, unsigned short* __restrict__ h16out,
        const float* __restrict__ gma, const float* __restrict__ bta,
        unsigned* __restrict__ ticket) {
    __shared__ unsigned short lds[2*10240];
    int j = blockIdx.x, g = blockIdx.y;
    int t = threadIdx.x, w = t >> 6, l = t & 63;
    int lg = l >> 4, c = l & 15;
    const unsigned short* pbase = WF + ((size_t)j*128 + g*16)*16384;

    {
        const unsigned short* src = pbase;
        #pragma unroll
        for (int q = 0; q < 4; ++q)
            GLD_LDS16(src + (size_t)(q*256 + t)*8, &lds[(q*256 + t)*8]);
        const unsigned short* hsrc = h16in + ((size_t)(t&7)*NUM_SLOTS + g*16)*D_MODEL + (t>>3)*8;
        GLD_LDS16(hsrc, &lds[8192 + t*8]);
    }
    __builtin_amdgcn_sched_barrier(0);
    f16x8 bqn[4];
    #pragma unroll
    for (int nt = 0; nt < 4; ++nt)
        bqn[nt] = *(const f16x8*)(pbase + 8192 + (size_t)((w*4+nt)*64 + l)*8);
    __builtin_amdgcn_sched_barrier(0);

    f32x4 acc[4];
    #pragma unroll
    for (int nt = 0; nt < 4; ++nt) acc[nt] = (f32x4){0.f,0.f,0.f,0.f};
    f16x8 hzero;
    #pragma unroll
    for (int e = 0; e < 8; ++e) hzero[e] = (_Float16)0.f;

    #pragma unroll 2
    for (int ii = 0; ii < 16; ++ii) {
        int cur = ii & 1;
        asm volatile("s_waitcnt vmcnt(4) lgkmcnt(0)" ::: "memory");
        __builtin_amdgcn_s_barrier();
        __builtin_amdgcn_sched_barrier(0);
        if (ii < 15) {
            const unsigned short* src = pbase + (size_t)(ii+1)*16384;
            unsigned short* dst = &lds[(cur^1)*10240];
            #pragma unroll
            for (int q = 0; q < 4; ++q)
                GLD_LDS16(src + (size_t)(q*256 + t)*8, dst + (size_t)(q*256 + t)*8);
            const unsigned short* hsrc = h16in + ((size_t)(t&7)*NUM_SLOTS + (g*16+ii+1))*D_MODEL + (t>>3)*8;
            GLD_LDS16(hsrc, dst + 8192 + (size_t)t*8);
        }
        __builtin_amdgcn_sched_barrier(0);
        f16x8 bq[4];
        #pragma unroll
        for (int nt = 0; nt < 4; ++nt) bq[nt] = bqn[nt];
        if (ii < 15) {
            const unsigned short* bp = pbase + (size_t)(ii+1)*16384 + 8192;
            #pragma unroll
            for (int nt = 0; nt < 4; ++nt)
                bqn[nt] = *(const f16x8*)(bp + (size_t)((w*4+nt)*64 + l)*8);
        }
        const unsigned short* buf = &lds[cur*10240];
        f32x4 d1[2];
        d1[0] = (f32x4){0.f,0.f,0.f,0.f};
        d1[1] = (f32x4){0.f,0.f,0.f,0.f};
        #pragma unroll
        for (int ks = 0; ks < 8; ++ks) {
            f16x8 a0 = *(const f16x8*)(buf + (size_t)((ks*2+0)*64 + l)*8);
            f16x8 a1 = *(const f16x8*)(buf + (size_t)((ks*2+1)*64 + l)*8);
            f16x8 hv = *(const f16x8*)(buf + 8192 + (size_t)(((ks*4+lg)*8 + (c&7)))*8);
            f16x8 hb = (c < 8) ? hv : hzero;
            d1[0] = __builtin_amdgcn_mfma_f32_16x16x32_f16(a0, hb, d1[0], 0, 0, 0);
            d1[1] = __builtin_amdgcn_mfma_f32_16x16x32_f16(a1, hb, d1[1], 0, 0, 0);
        }
        unsigned q0 = pk2(d1[0][0], d1[0][1]);
        unsigned q1 = pk2(d1[0][2], d1[0][3]);
        unsigned s0 = pk2(d1[1][0], d1[1][1]);
        unsigned s1 = pk2(d1[1][2], d1[1][3]);
        int srcLo = 32*(lg & 1) + c;
        int srcHi = srcLo + 16;
        unsigned a0s = (unsigned)__shfl((int)q0, srcLo, 64);
        unsigned a1s = (unsigned)__shfl((int)q1, srcLo, 64);
        unsigned a2s = (unsigned)__shfl((int)q0, srcHi, 64);
        unsigned a3s = (unsigned)__shfl((int)q1, srcHi, 64);
        unsigned b0s = (unsigned)__shfl((int)s0, srcLo, 64);
        unsigned b1s = (unsigned)__shfl((int)s1, srcLo, 64);
        unsigned b2s = (unsigned)__shfl((int)s0, srcHi, 64);
        unsigned b3s = (unsigned)__shfl((int)s1, srcHi, 64);
        bool himt = ((lg >> 1) & 1);
        union { unsigned u[4]; f16x8 v; } A2u;
        A2u.u[0] = himt ? b0s : a0s;
        A2u.u[1] = himt ? b1s : a1s;
        A2u.u[2] = himt ? b2s : a2s;
        A2u.u[3] = himt ? b3s : a3s;
        #pragma unroll
        for (int nt = 0; nt < 4; ++nt)
            acc[nt] = __builtin_amdgcn_mfma_f32_16x16x32_f16(A2u.v, bq[nt], acc[nt], 0, 0, 0);
    }
    if (lg < 2) {
        #pragma unroll
        for (int nt = 0; nt < 4; ++nt) {
            int d = (w*4 + nt)*16 + c;
            #pragma unroll
            for (int r = 0; r < 4; ++r) {
                int b = lg*4 + r;
                part[(((size_t)g*BATCH + b)*NUM_SLOTS + j)*D_MODEL + d] = acc[nt][r];
            }
        }
    }
    // ---- fused LN tail (finisher pattern) ----
    __threadfence();               // publish this block's part stores
    __syncthreads();
    __shared__ unsigned lastFlag;
    if (t == 0) {
        unsigned prev = atomicAdd(&ticket[j], 1u);
        lastFlag = (prev == IGROUPS - 1) ? 1u : 0u;
    }
    __syncthreads();
    if (lastFlag) {
        if (t == 0) atomicExch(&ticket[j], 0u);   // device-scope reset
        __threadfence();               // acquire: see all 8 blocks' parts
        float* red = (float*)lds;
        for (int b = 0; b < BATCH; ++b) {
            int bj = b*NUM_SLOTS + j;
            float v = 0.f;
            #pragma unroll
            for (int g2 = 0; g2 < IGROUPS; ++g2)
                v += part[(((size_t)g2*BATCH + b)*NUM_SLOTS + j)*D_MODEL + t];
            float x = Hst[(size_t)bj*D_MODEL + t] + fmaxf(v, 0.f);
            red[t] = x; __syncthreads();
            for (int o = 128; o > 0; o >>= 1) { if (t < o) red[t] += red[t+o]; __syncthreads(); }
            float mu = red[0] * (1.0f/D_MODEL); __syncthreads();
            float dx = x - mu;
            red[t] = dx*dx; __syncthreads();
            for (int o = 128; o > 0; o >>= 1) { if (t < o) red[t] += red[t+o]; __syncthreads(); }
            float var = red[0] * (1.0f/D_MODEL);
            float outv = dx * rsqrtf(var + LN_EPS) * gma[t] + bta[t];
            Hst[(size_t)bj*D_MODEL + t] = outv;
            h16out[(size_t)bj*D_MODEL + t] = f2h(outv);
            __syncthreads();           // red reuse next row
        }
    }
}

// Kf/Vf projections from Hst, selected by blockIdx.z (frozen)
__global__ __launch_bounds__(256) void k_kfvf(const float* __restrict__ A,
        const float* __restrict__ B0, const float* __restrict__ B1,
        float* __restrict__ C0, float* __restrict__ C1) {
    const int K = D_MODEL, N = D_MODEL;
    const float* B = blockIdx.z == 0 ? B0 : B1;
    float* C = blockIdx.z == 0 ? C0 : C1;
    __shared__ float As[32][64];
    __shared__ float Bs[32][64];
    int bm = blockIdx.x * 64, bn = blockIdx.y * 64;
    int t = threadIdx.x;
    int tm = (t & 15) * 4, tn = (t >> 4) * 4;
    float acc[4][4] = {};
    for (int k0 = 0; k0 < K; k0 += 32) {
        #pragma unroll
        for (int r = 0; r < 8; ++r) {
            int idx = r*256 + t;
            int m = idx >> 5, k = idx & 31;
            As[k][m] = A[(size_t)(bm+m)*K + k0 + k];
        }
        #pragma unroll
        for (int r = 0; r < 8; ++r) {
            int idx = r*256 + t;
            int n = idx >> 5, k = idx & 31;
            Bs[k][n] = B[(size_t)(bn+n)*K + k0 + k];
        }
        __syncthreads();
        #pragma unroll
        for (int k = 0; k < 32; ++k) {
            float4 a4 = *(const float4*)&As[k][tm];
            float4 b4 = *(const float4*)&Bs[k][tn];
            float a[4] = {a4.x,a4.y,a4.z,a4.w};
            float b[4] = {b4.x,b4.y,b4.z,b4.w};
            #pragma unroll
            for (int i = 0; i < 4; ++i)
                #pragma unroll
                for (int jj = 0; jj < 4; ++jj)
                    acc[i][jj] += a[i]*b[jj];
        }
        __syncthreads();
    }
    #pragma unroll
    for (int i = 0; i < 4; ++i) {
        float4 v = make_float4(acc[i][0],acc[i][1],acc[i][2],acc[i][3]);
        *(float4*)&C[(size_t)(bm+tm+i)*N + bn+tn] = v;
    }
}

// fused expand attention: scores -> softmax -> Y, written as fp16 (frozen)
__global__ __launch_bounds__(256) void k_attn2y(const float* __restrict__ Q,
        const float* __restrict__ Kf, const float* __restrict__ Vf,
        unsigned short* __restrict__ Yh) {
    int bl = blockIdx.x; int b = bl / SEQ;
    int t = threadIdx.x;
    __shared__ float q[D_MODEL];
    __shared__ float prt[2][128];
    __shared__ float a[128];
    __shared__ float red[128];
    q[t] = Q[(size_t)bl*D_MODEL + t];
    __syncthreads();
    int s = t & 127, hf = t >> 7;
    const float* kf = Kf + ((size_t)b*NUM_SLOTS + s)*D_MODEL + hf*128;
    float accp = 0.f;
    #pragma unroll 8
    for (int d = 0; d < 128; ++d) accp += q[hf*128 + d]*kf[d];
    prt[hf][s] = accp;
    __syncthreads();
    float v = 0.f;
    if (t < 128) { v = (prt[0][t] + prt[1][t]) * SM_SCALE; red[t] = v; }
    __syncthreads();
    for (int o = 64; o > 0; o >>= 1) { if (t < o) red[t] = fmaxf(red[t], red[t+o]); __syncthreads(); }
    float mx = red[0]; __syncthreads();
    if (t < 128) { float e = expf(v - mx); a[t] = e; red[t] = e; }
    __syncthreads();
    for (int o = 64; o > 0; o >>= 1) { if (t < o) red[t] += red[t+o]; __syncthreads(); }
    float inv = 1.0f / red[0];
    __syncthreads();
    const float* vf = Vf + (size_t)b*NUM_SLOTS*D_MODEL + t;
    float y0 = 0.f, y1 = 0.f, y2 = 0.f, y3 = 0.f;
    #pragma unroll
    for (int s2 = 0; s2 < NUM_SLOTS; s2 += 4) {
        y0 += a[s2+0]*vf[(size_t)(s2+0)*D_MODEL];
        y1 += a[s2+1]*vf[(size_t)(s2+1)*D_MODEL];
        y2 += a[s2+2]*vf[(size_t)(s2+2)*D_MODEL];
        y3 += a[s2+3]*vf[(size_t)(s2+3)*D_MODEL];
    }
    float y = ((y0+y1) + (y2+y3)) * inv;
    Yh[(size_t)bl*D_MODEL + t] = f2h(y);
}

extern "C" void kernel_launch(void* const* d_in, const int* in_sizes, int n_in,
                              void* d_out, int out_size, void* d_ws, size_t ws_size,
                              hipStream_t stream) {
    const int*   ids    = (const int*)d_in[0];
    const int*   amask  = (const int*)d_in[1];
    const float* tok    = (const float*)d_in[2];
    const float* pos    = (const float*)d_in[3];
    const float* Hin    = (const float*)d_in[4];
    const float* Ws     = (const float*)d_in[5];
    const float* Wt     = (const float*)d_in[6];
    const float* Wq_in  = (const float*)d_in[7];
    const float* Wk_sl  = (const float*)d_in[8];
    const float* Wv_in  = (const float*)d_in[9];
    const float* Wq_out = (const float*)d_in[10];
    const float* Wk_fin = (const float*)d_in[11];
    const float* Wv_fin = (const float*)d_in[12];
    const float* Wop    = (const float*)d_in[13];
    const float* lnsc   = (const float*)d_in[14];
    const float* lnbs   = (const float*)d_in[15];
    float* out = (float*)d_out;

    const size_t WF_USH = (size_t)16384 * 16384;     // 512 MiB of ushorts
    unsigned short* WF = (unsigned short*)d_ws;
    float* ws = (float*)(WF + WF_USH);

    float* X    = ws;
    float* Qin  = X    + (size_t)NTOK*D_MODEL;
    float* Vin  = Qin  + (size_t)NTOK*D_MODEL;
    float* Ksl  = Vin  + (size_t)NTOK*D_MODEL;
    float* Asc  = Ksl  + (size_t)NUM_SLOTS*D_MODEL;
    float* csp  = Asc  + (size_t)NTOK*NUM_SLOTS;
    float* Hst  = csp  + (size_t)BATCH*8*NUM_SLOTS;
    float* part = Hst  + (size_t)BATCH*NUM_SLOTS*D_MODEL;
    float* Qout = part + (size_t)IGROUPS*BATCH*NUM_SLOTS*D_MODEL;
    float* Kf   = Qout + (size_t)NTOK*D_MODEL;
    float* Vf   = Kf   + (size_t)BATCH*NUM_SLOTS*D_MODEL;
    float* A2   = Vf   + (size_t)BATCH*NUM_SLOTS*D_MODEL;
    float* Yb   = A2   + (size_t)NTOK*NUM_SLOTS;
    unsigned short* Yh = (unsigned short*)(Yb + (size_t)NTOK*D_MODEL);
    unsigned short* Yl = Yh + (size_t)NTOK*D_MODEL;
    unsigned short* Wf16 = Yl + (size_t)NTOK*D_MODEL;
    unsigned short* Hst16A = Wf16 + (size_t)VOCAB*D_MODEL;
    unsigned short* Hst16B = Hst16A + (size_t)BATCH*NUM_SLOTS*D_MODEL;
    unsigned* ticket = (unsigned*)(Hst16B + (size_t)BATCH*NUM_SLOTS*D_MODEL);

    // front phase: serial small-kernel chain, each overlapped with a slice
    // of the independent weight-conversion blocks
    k_front_a<<<768 + NC_A, 256, 0, stream>>>(ids, tok, pos,
            Wq_in, Wv_in, Wq_out, Qin, Vin, Qout, Ws, Wt, WF, ticket);
    k_front_b<<<8008 + NC_B, 256, 0, stream>>>(Hin, Wk_sl, Ksl, Wop, Wf16, Ws, Wt, WF);
    k_front_c<<<NTOK + NC_C, 256, 0, stream>>>(Qin, Ksl, amask, Asc, Ws, Wt, WF);
    k_front_d<<<BATCH*NUM_SLOTS + NC_D, 256, 0, stream>>>(Asc, Vin, Hin, Hst, Hst16A, Ws, Wt, WF);

    // bilinear slot-interaction steps (LN fused; h16 ping-pong eliminates race)
    for (int st = 0; st < N_STEPS; ++st) {
        unsigned short* hin  = (st & 1) ? Hst16B : Hst16A;
        unsigned short* hout = (st & 1) ? Hst16A : Hst16B;
        k_pairs_mfma<<<dim3(NUM_SLOTS, IGROUPS), 256, 0, stream>>>(hin, WF, part,
                Hst, hout, lnsc + st*D_MODEL, lnbs + st*D_MODEL, ticket);
    }

    // expand projections (Kf, Vf fused)
    k_kfvf<<<dim3(BATCH*NUM_SLOTS/64, 4, 2), 256, 0, stream>>>(Hst, Wk_fin, Wv_fin, Kf, Vf);
    // fused expand attention + Y (fp16)
    k_attn2y<<<NTOK, 256, 0, stream>>>(Qout, Kf, Vf, Yh);
    // logits: 1-pass fp16 MFMA with global_load_lds staging
    k_logits<<<dim3(NTOK/128, VOCAB/128), 256, 0, stream>>>(Yh, Wf16, out);
}

// Round 17
// 1351.043 us; speedup vs baseline: 1.8846x; 1.8846x over previous
//
#include <hip/hip_runtime.h>
#include <hip/hip_bf16.h>
#include <math.h>

#define D_MODEL 256
#define NUM_SLOTS 128
#define RANK 32
#define N_STEPS 6
#define VOCAB 32000
#define SEQ 512
#define BATCH 8
#define NTOK (BATCH*SEQ)
#define LN_EPS 1e-5f
#define SM_SCALE 0.0625f
#define IGROUPS 8

// convert block distribution across the four front dispatches
#define CB_A 0
#define NC_A 15360
#define CB_B (CB_A + NC_A)
#define NC_B 11776
#define CB_C (CB_B + NC_B)
#define NC_C 19200
#define CB_D (CB_C + NC_C)
#define NC_D 19200

typedef __attribute__((ext_vector_type(8))) short bf16x8;
typedef __attribute__((ext_vector_type(8))) _Float16 f16x8;
typedef __attribute__((ext_vector_type(4))) float f32x4;

#define GLD_LDS16(g, l) __builtin_amdgcn_global_load_lds( \
    (const __attribute__((address_space(1))) unsigned int*)(g), \
    (__attribute__((address_space(3))) unsigned int*)(l), 16, 0, 0)

__device__ inline unsigned pk2(float a, float b) {
    auto v = __builtin_amdgcn_cvt_pkrtz(a, b);
    union { decltype(v) x; unsigned u; } c;
    c.x = v;
    return c.u;
}
__device__ inline unsigned short f2h(float x) {
    union { _Float16 h; unsigned short u; } c;
    c.h = (_Float16)x;
    return c.u;
}

// ---- convert device body (frozen logic) ----
__device__ __forceinline__ void dev_convert(int cb, int t, float* ldsAll,
        const float* __restrict__ Ws, const float* __restrict__ Wt,
        unsigned short* __restrict__ WF) {
    int z = cb >> 14, i = (cb >> 7) & 127, j = cb & 127;
    int w = t >> 6, l = t & 63;
    float* lw = &ldsAll[w*1056];
    size_t sBase = ((size_t)i*128 + j)*8192;
    size_t pOut = ((size_t)j*128 + i)*16384;
    int g = l >> 4, c = l & 15;
    if (z < 2) {
        int ks = z*4 + w;
        const float4* s4 = (const float4*)(Ws + sBase) + ks*256;
        #pragma unroll
        for (int q = 0; q < 4; ++q) {
            int idx = q*64 + l;
            float4 v = s4[idx];
            *(float4*)&lw[(idx>>3)*33 + 4*(idx&7)] = v;
        }
        asm volatile("s_waitcnt lgkmcnt(0)" ::: "memory");
        bool diag = (i == j);
        #pragma unroll
        for (int mt = 0; mt < 2; ++mt) {
            union { f16x8 v; } o;
            #pragma unroll
            for (int e = 0; e < 8; ++e) {
                float f = diag ? 0.f : lw[(g*8 + e)*33 + mt*16 + c];
                o.v[e] = (_Float16)f;
            }
            *(f16x8*)(WF + pOut + (size_t)((ks*2 + mt)*64 + l)*8) = o.v;
        }
    } else {
        int p0 = (z - 2)*8 + w*2;
        const float4* s4 = (const float4*)(Wt + sBase);
        #pragma unroll
        for (int q = 0; q < 4; ++q) {
            int idx = q*64 + l;
            int r = idx >> 3, c8 = idx & 7;
            float4 v = s4[r*64 + p0*4 + c8];
            *(float4*)&lw[r*33 + 4*c8] = v;
        }
        asm volatile("s_waitcnt lgkmcnt(0)" ::: "memory");
        #pragma unroll
        for (int dn = 0; dn < 2; ++dn) {
            int nt = p0 + dn;
            union { f16x8 v; } o;
            #pragma unroll
            for (int e = 0; e < 8; ++e)
                o.v[e] = (_Float16)lw[(g*8 + e)*33 + dn*16 + c];
            *(f16x8*)(WF + pOut + 8192 + (size_t)(nt*64 + l)*8) = o.v;
        }
    }
}

// ---- front A: gemm3e (embed-fused Qin/Vin/Qout projections) + convert ----
__global__ __launch_bounds__(256) void k_front_a(const int* __restrict__ ids,
        const float* __restrict__ tok, const float* __restrict__ pos,
        const float* __restrict__ B0, const float* __restrict__ B1,
        const float* __restrict__ B2, float* __restrict__ C0,
        float* __restrict__ C1, float* __restrict__ C2,
        const float* __restrict__ Ws, const float* __restrict__ Wt,
        unsigned short* __restrict__ WF) {
    __shared__ float smem[4352];
    int bid = blockIdx.x;
    int t = threadIdx.x;
    if (bid >= 768) { dev_convert(CB_A + bid - 768, t, smem, Ws, Wt, WF); return; }
    const int K = D_MODEL, N = D_MODEL;
    int bx = bid & 63, byz = bid >> 6;
    int by = byz & 3, bz = byz >> 2;
    const float* B = bz == 0 ? B0 : (bz == 1 ? B1 : B2);
    float* C = bz == 0 ? C0 : (bz == 1 ? C1 : C2);
    float* As = smem;
    float* Bs = smem + 2048;
    int* sid = (int*)(smem + 4096);
    int bm = bx * 64, bn = by * 64;
    if (t < 64) sid[t] = ids[bm + t];
    __syncthreads();
    int tm = (t & 15) * 4, tn = (t >> 4) * 4;
    float acc[4][4] = {};
    for (int k0 = 0; k0 < K; k0 += 32) {
        #pragma unroll
        for (int r = 0; r < 8; ++r) {
            int idx = r*256 + t;
            int m = idx >> 5, k = idx & 31;
            int gm = bm + m;
            As[k*64 + m] = tok[(size_t)sid[m]*K + k0 + k] + pos[(gm & (SEQ-1))*K + k0 + k];
        }
        #pragma unroll
        for (int r = 0; r < 8; ++r) {
            int idx = r*256 + t;
            int n = idx >> 5, k = idx & 31;
            Bs[k*64 + n] = B[(size_t)(bn+n)*K + k0 + k];
        }
        __syncthreads();
        #pragma unroll
        for (int k = 0; k < 32; ++k) {
            float4 a4 = *(const float4*)&As[k*64 + tm];
            float4 b4 = *(const float4*)&Bs[k*64 + tn];
            float a[4] = {a4.x,a4.y,a4.z,a4.w};
            float b[4] = {b4.x,b4.y,b4.z,b4.w};
            #pragma unroll
            for (int i = 0; i < 4; ++i)
                #pragma unroll
                for (int jj = 0; jj < 4; ++jj)
                    acc[i][jj] += a[i]*b[jj];
        }
        __syncthreads();
    }
    #pragma unroll
    for (int i = 0; i < 4; ++i) {
        float4 v = make_float4(acc[i][0],acc[i][1],acc[i][2],acc[i][3]);
        *(float4*)&C[(size_t)(bm+tm+i)*N + bn+tn] = v;
    }
}

// ---- front B: Ksl projection + W_out fp16 split + convert ----
__global__ __launch_bounds__(256) void k_front_b(const float* __restrict__ Hin,
        const float* __restrict__ Wk_sl, float* __restrict__ Ksl,
        const float* __restrict__ Wop, unsigned short* __restrict__ Wf16,
        const float* __restrict__ Ws, const float* __restrict__ Wt,
        unsigned short* __restrict__ WF) {
    __shared__ float smem[4352];
    int bid = blockIdx.x;
    int t = threadIdx.x;
    if (bid >= 8008) { dev_convert(CB_B + bid - 8008, t, smem, Ws, Wt, WF); return; }
    if (bid >= 8) {
        int i = (bid - 8)*256 + t;
        float4 v = ((const float4*)Wop)[i];
        ushort4 h;
        h.x = f2h(v.x); h.y = f2h(v.y); h.z = f2h(v.z); h.w = f2h(v.w);
        ((ushort4*)Wf16)[i] = h;
        return;
    }
    const int K = D_MODEL, N = D_MODEL;
    int bx = bid & 1, by = bid >> 1;
    float* As = smem;
    float* Bs = smem + 2048;
    int bm = bx * 64, bn = by * 64;
    int tm = (t & 15) * 4, tn = (t >> 4) * 4;
    float acc[4][4] = {};
    for (int k0 = 0; k0 < K; k0 += 32) {
        #pragma unroll
        for (int r = 0; r < 8; ++r) {
            int idx = r*256 + t;
            int m = idx >> 5, k = idx & 31;
            As[k*64 + m] = Hin[(size_t)(bm+m)*K + k0 + k];
        }
        #pragma unroll
        for (int r = 0; r < 8; ++r) {
            int idx = r*256 + t;
            int n = idx >> 5, k = idx & 31;
            Bs[k*64 + n] = Wk_sl[(size_t)(bn+n)*K + k0 + k];
        }
        __syncthreads();
        #pragma unroll
        for (int k = 0; k < 32; ++k) {
            float4 a4 = *(const float4*)&As[k*64 + tm];
            float4 b4 = *(const float4*)&Bs[k*64 + tn];
            float a[4] = {a4.x,a4.y,a4.z,a4.w};
            float b[4] = {b4.x,b4.y,b4.z,b4.w};
            #pragma unroll
            for (int i = 0; i < 4; ++i)
                #pragma unroll
                for (int jj = 0; jj < 4; ++jj)
                    acc[i][jj] += a[i]*b[jj];
        }
        __syncthreads();
    }
    #pragma unroll
    for (int i = 0; i < 4; ++i) {
        float4 v = make_float4(acc[i][0],acc[i][1],acc[i][2],acc[i][3]);
        *(float4*)&Ksl[(size_t)(bm+tm+i)*N + bn+tn] = v;
    }
}

// ---- front C: compress attention (scores+softmax+mask) + convert ----
__global__ __launch_bounds__(256) void k_front_c(const float* __restrict__ Qin,
        const float* __restrict__ Ksl, const int* __restrict__ mask,
        float* __restrict__ A,
        const float* __restrict__ Ws, const float* __restrict__ Wt,
        unsigned short* __restrict__ WF) {
    __shared__ float smem[4352];
    int bid = blockIdx.x;
    int t = threadIdx.x;
    if (bid >= NTOK) { dev_convert(CB_C + bid - NTOK, t, smem, Ws, Wt, WF); return; }
    int bl = bid;
    float* q   = smem;
    float* prt = smem + 256;
    float* red = smem + 512;
    q[t] = Qin[(size_t)bl*D_MODEL + t];
    __syncthreads();
    int s = t & 127, hf = t >> 7;
    const float* kr = Ksl + (size_t)s*D_MODEL + hf*128;
    float accp = 0.f;
    #pragma unroll 8
    for (int d = 0; d < 128; ++d) accp += q[hf*128 + d]*kr[d];
    prt[hf*128 + s] = accp;
    __syncthreads();
    float v = 0.f;
    if (t < 128) { v = (prt[t] + prt[128 + t]) * SM_SCALE; red[t] = v; }
    __syncthreads();
    for (int o = 64; o > 0; o >>= 1) { if (t < o) red[t] = fmaxf(red[t], red[t+o]); __syncthreads(); }
    float mx = red[0]; __syncthreads();
    float e = 0.f;
    if (t < 128) { e = expf(v - mx); red[t] = e; }
    __syncthreads();
    for (int o = 64; o > 0; o >>= 1) { if (t < o) red[t] += red[t+o]; __syncthreads(); }
    float sum = red[0];
    if (t < 128) {
        float m = (float)mask[bl];
        A[(size_t)bl*NUM_SLOTS + t] = e / sum * m;
    }
}

// ---- front D: slot aggregation (IR, colsum fused) + convert ----
__global__ __launch_bounds__(256) void k_front_d(const float* __restrict__ A,
        const float* __restrict__ V, const float* __restrict__ H,
        float* __restrict__ Hs, unsigned short* __restrict__ Hs16,
        const float* __restrict__ Ws, const float* __restrict__ Wt,
        unsigned short* __restrict__ WF) {
    __shared__ float smem[4352];
    int bid = blockIdx.x;
    int t = threadIdx.x;
    if (bid >= BATCH*NUM_SLOTS) { dev_convert(CB_D + bid - BATCH*NUM_SLOTS, t, smem, Ws, Wt, WF); return; }
    int bs = bid; int b = bs >> 7; int s = bs & 127;
    int d = t;
    const float* Ab = A + (size_t)b*SEQ*NUM_SLOTS + s;
    const float* Vb = V + (size_t)b*SEQ*D_MODEL + d;
    float a0 = 0.f, a1 = 0.f, a2 = 0.f, a3 = 0.f;
    float s0 = 0.f, s1 = 0.f, s2 = 0.f, s3 = 0.f;
    for (int l = 0; l < SEQ; l += 4) {
        float w0 = Ab[(size_t)(l+0)*NUM_SLOTS];
        float w1 = Ab[(size_t)(l+1)*NUM_SLOTS];
        float w2 = Ab[(size_t)(l+2)*NUM_SLOTS];
        float w3 = Ab[(size_t)(l+3)*NUM_SLOTS];
        a0 += w0 * Vb[(size_t)(l+0)*D_MODEL];
        a1 += w1 * Vb[(size_t)(l+1)*D_MODEL];
        a2 += w2 * Vb[(size_t)(l+2)*D_MODEL];
        a3 += w3 * Vb[(size_t)(l+3)*D_MODEL];
        s0 += w0; s1 += w1; s2 += w2; s3 += w3;
    }
    float asum = (s0+s1) + (s2+s3) + 1e-8f;
    float acc = (a0+a1) + (a2+a3);
    float v = H[s*D_MODEL + d] + acc / asum;
    Hs[(size_t)bs*D_MODEL + d] = v;
    Hs16[(size_t)bs*D_MODEL + d] = f2h(v);
}

// logits GEMM: 1-pass fp16 MFMA, global_load_lds staging (frozen)
__global__ __launch_bounds__(256) void k_logits(
        const unsigned short* __restrict__ Ahg,
        const unsigned short* __restrict__ Bhg, float* __restrict__ C) {
    __shared__ unsigned short lds[2*8192];
    int bm = blockIdx.x * 128, bn = blockIdx.y * 128;
    int t = threadIdx.x;
    int w = t >> 6, l = t & 63;
    int wr = w >> 1, wc = w & 1;
    int lr = l & 15, lk = l >> 4;
    f32x4 acc[4][4];
    #pragma unroll
    for (int mi = 0; mi < 4; ++mi)
        #pragma unroll
        for (int ni = 0; ni < 4; ++ni)
            acc[mi][ni] = (f32x4){0.f,0.f,0.f,0.f};

    for (int kc = 0; kc < 4; ++kc) {
        if (kc) __syncthreads();
        #pragma unroll
        for (int i = 0; i < 4; ++i) {
            int c = t + i*256;
            int row = c >> 3, c8 = c & 7;
            size_t ga = (size_t)(bm+row)*256 + kc*64 + c8*8;
            size_t gb = (size_t)(bn+row)*256 + kc*64 + c8*8;
            GLD_LDS16(Ahg + ga, &lds[c*8]);
            GLD_LDS16(Bhg + gb, &lds[8192 + c*8]);
        }
        __syncthreads();
        #pragma unroll
        for (int s = 0; s < 2; ++s) {
            f16x8 ah[4], bh[4];
            #pragma unroll
            for (int mi = 0; mi < 4; ++mi) {
                int off = (wr*64 + mi*16 + lr)*64 + s*32 + lk*8;
                ah[mi] = *(const f16x8*)&lds[off];
            }
            #pragma unroll
            for (int ni = 0; ni < 4; ++ni) {
                int off = (wc*64 + ni*16 + lr)*64 + s*32 + lk*8;
                bh[ni] = *(const f16x8*)&lds[8192 + off];
            }
            #pragma unroll
            for (int mi = 0; mi < 4; ++mi)
                #pragma unroll
                for (int ni = 0; ni < 4; ++ni)
                    acc[mi][ni] = __builtin_amdgcn_mfma_f32_16x16x32_f16(ah[mi], bh[ni], acc[mi][ni], 0, 0, 0);
        }
    }
    #pragma unroll
    for (int mi = 0; mi < 4; ++mi)
        #pragma unroll
        for (int ni = 0; ni < 4; ++ni) {
            int col = bn + wc*64 + ni*16 + lr;
            #pragma unroll
            for (int r = 0; r < 4; ++r) {
                int row = bm + wr*64 + mi*16 + lk*4 + r;
                C[(size_t)row*VOCAB + col] = acc[mi][ni][r];
            }
        }
}

// ---- MFMA slot-pair kernel (frozen structure) ----
__global__ __launch_bounds__(256, 4) void k_pairs_mfma(const unsigned short* __restrict__ h16,
        const unsigned short* __restrict__ WF, float* __restrict__ part) {
    __shared__ unsigned short lds[2*10240];
    int j = blockIdx.x, g = blockIdx.y;
    int t = threadIdx.x, w = t >> 6, l = t & 63;
    int lg = l >> 4, c = l & 15;
    const unsigned short* pbase = WF + ((size_t)j*128 + g*16)*16384;

    {
        const unsigned short* src = pbase;
        #pragma unroll
        for (int q = 0; q < 4; ++q)
            GLD_LDS16(src + (size_t)(q*256 + t)*8, &lds[(q*256 + t)*8]);
        const unsigned short* hsrc = h16 + ((size_t)(t&7)*NUM_SLOTS + g*16)*D_MODEL + (t>>3)*8;
        GLD_LDS16(hsrc, &lds[8192 + t*8]);
    }
    __builtin_amdgcn_sched_barrier(0);
    f16x8 bqn[4];
    #pragma unroll
    for (int nt = 0; nt < 4; ++nt)
        bqn[nt] = *(const f16x8*)(pbase + 8192 + (size_t)((w*4+nt)*64 + l)*8);
    __builtin_amdgcn_sched_barrier(0);

    f32x4 acc[4];
    #pragma unroll
    for (int nt = 0; nt < 4; ++nt) acc[nt] = (f32x4){0.f,0.f,0.f,0.f};
    f16x8 hzero;
    #pragma unroll
    for (int e = 0; e < 8; ++e) hzero[e] = (_Float16)0.f;

    #pragma unroll 2
    for (int ii = 0; ii < 16; ++ii) {
        int cur = ii & 1;
        asm volatile("s_waitcnt vmcnt(4) lgkmcnt(0)" ::: "memory");
        __builtin_amdgcn_s_barrier();
        __builtin_amdgcn_sched_barrier(0);
        if (ii < 15) {
            const unsigned short* src = pbase + (size_t)(ii+1)*16384;
            unsigned short* dst = &lds[(cur^1)*10240];
            #pragma unroll
            for (int q = 0; q < 4; ++q)
                GLD_LDS16(src + (size_t)(q*256 + t)*8, dst + (size_t)(q*256 + t)*8);
            const unsigned short* hsrc = h16 + ((size_t)(t&7)*NUM_SLOTS + (g*16+ii+1))*D_MODEL + (t>>3)*8;
            GLD_LDS16(hsrc, dst + 8192 + (size_t)t*8);
        }
        __builtin_amdgcn_sched_barrier(0);
        f16x8 bq[4];
        #pragma unroll
        for (int nt = 0; nt < 4; ++nt) bq[nt] = bqn[nt];
        if (ii < 15) {
            const unsigned short* bp = pbase + (size_t)(ii+1)*16384 + 8192;
            #pragma unroll
            for (int nt = 0; nt < 4; ++nt)
                bqn[nt] = *(const f16x8*)(bp + (size_t)((w*4+nt)*64 + l)*8);
        }
        const unsigned short* buf = &lds[cur*10240];
        f32x4 d1[2];
        d1[0] = (f32x4){0.f,0.f,0.f,0.f};
        d1[1] = (f32x4){0.f,0.f,0.f,0.f};
        #pragma unroll
        for (int ks = 0; ks < 8; ++ks) {
            f16x8 a0 = *(const f16x8*)(buf + (size_t)((ks*2+0)*64 + l)*8);
            f16x8 a1 = *(const f16x8*)(buf + (size_t)((ks*2+1)*64 + l)*8);
            f16x8 hv = *(const f16x8*)(buf + 8192 + (size_t)(((ks*4+lg)*8 + (c&7)))*8);
            f16x8 hb = (c < 8) ? hv : hzero;
            d1[0] = __builtin_amdgcn_mfma_f32_16x16x32_f16(a0, hb, d1[0], 0, 0, 0);
            d1[1] = __builtin_amdgcn_mfma_f32_16x16x32_f16(a1, hb, d1[1], 0, 0, 0);
        }
        unsigned q0 = pk2(d1[0][0], d1[0][1]);
        unsigned q1 = pk2(d1[0][2], d1[0][3]);
        unsigned s0 = pk2(d1[1][0], d1[1][1]);
        unsigned s1 = pk2(d1[1][2], d1[1][3]);
        int srcLo = 32*(lg & 1) + c;
        int srcHi = srcLo + 16;
        unsigned a0s = (unsigned)__shfl((int)q0, srcLo, 64);
        unsigned a1s = (unsigned)__shfl((int)q1, srcLo, 64);
        unsigned a2s = (unsigned)__shfl((int)q0, srcHi, 64);
        unsigned a3s = (unsigned)__shfl((int)q1, srcHi, 64);
        unsigned b0s = (unsigned)__shfl((int)s0, srcLo, 64);
        unsigned b1s = (unsigned)__shfl((int)s1, srcLo, 64);
        unsigned b2s = (unsigned)__shfl((int)s0, srcHi, 64);
        unsigned b3s = (unsigned)__shfl((int)s1, srcHi, 64);
        bool himt = ((lg >> 1) & 1);
        union { unsigned u[4]; f16x8 v; } A2u;
        A2u.u[0] = himt ? b0s : a0s;
        A2u.u[1] = himt ? b1s : a1s;
        A2u.u[2] = himt ? b2s : a2s;
        A2u.u[3] = himt ? b3s : a3s;
        #pragma unroll
        for (int nt = 0; nt < 4; ++nt)
            acc[nt] = __builtin_amdgcn_mfma_f32_16x16x32_f16(A2u.v, bq[nt], acc[nt], 0, 0, 0);
    }
    if (lg < 2) {
        #pragma unroll
        for (int nt = 0; nt < 4; ++nt) {
            int d = (w*4 + nt)*16 + c;
            #pragma unroll
            for (int r = 0; r < 4; ++r) {
                int b = lg*4 + r;
                part[(((size_t)g*BATCH + b)*NUM_SLOTS + j)*D_MODEL + d] = acc[nt][r];
            }
        }
    }
}

// h = LN(h + relu(sum_g part)); writes fp32 and fp16 copies (frozen)
__global__ __launch_bounds__(256) void k_ln(float* __restrict__ h,
        unsigned short* __restrict__ h16, const float* __restrict__ part,
        const float* __restrict__ gma, const float* __restrict__ bta) {
    int bj = blockIdx.x;
    int t = threadIdx.x;
    int b = bj >> 7, j = bj & 127;
    __shared__ float red[256];
    float v = 0.f;
    #pragma unroll
    for (int g = 0; g < IGROUPS; ++g)
        v += part[(((size_t)g*BATCH + b)*NUM_SLOTS + j)*D_MODEL + t];
    float x = h[(size_t)bj*D_MODEL + t] + fmaxf(v, 0.f);
    red[t] = x; __syncthreads();
    for (int o = 128; o > 0; o >>= 1) { if (t < o) red[t] += red[t+o]; __syncthreads(); }
    float mu = red[0] * (1.0f/D_MODEL); __syncthreads();
    float dx = x - mu;
    red[t] = dx*dx; __syncthreads();
    for (int o = 128; o > 0; o >>= 1) { if (t < o) red[t] += red[t+o]; __syncthreads(); }
    float var = red[0] * (1.0f/D_MODEL);
    float outv = dx * rsqrtf(var + LN_EPS) * gma[t] + bta[t];
    h[(size_t)bj*D_MODEL + t] = outv;
    h16[(size_t)bj*D_MODEL + t] = f2h(outv);
}

// Kf/Vf projections from Hst, selected by blockIdx.z (frozen)
__global__ __launch_bounds__(256) void k_kfvf(const float* __restrict__ A,
        const float* __restrict__ B0, const float* __restrict__ B1,
        float* __restrict__ C0, float* __restrict__ C1) {
    const int K = D_MODEL, N = D_MODEL;
    const float* B = blockIdx.z == 0 ? B0 : B1;
    float* C = blockIdx.z == 0 ? C0 : C1;
    __shared__ float As[32][64];
    __shared__ float Bs[32][64];
    int bm = blockIdx.x * 64, bn = blockIdx.y * 64;
    int t = threadIdx.x;
    int tm = (t & 15) * 4, tn = (t >> 4) * 4;
    float acc[4][4] = {};
    for (int k0 = 0; k0 < K; k0 += 32) {
        #pragma unroll
        for (int r = 0; r < 8; ++r) {
            int idx = r*256 + t;
            int m = idx >> 5, k = idx & 31;
            As[k][m] = A[(size_t)(bm+m)*K + k0 + k];
        }
        #pragma unroll
        for (int r = 0; r < 8; ++r) {
            int idx = r*256 + t;
            int n = idx >> 5, k = idx & 31;
            Bs[k][n] = B[(size_t)(bn+n)*K + k0 + k];
        }
        __syncthreads();
        #pragma unroll
        for (int k = 0; k < 32; ++k) {
            float4 a4 = *(const float4*)&As[k][tm];
            float4 b4 = *(const float4*)&Bs[k][tn];
            float a[4] = {a4.x,a4.y,a4.z,a4.w};
            float b[4] = {b4.x,b4.y,b4.z,b4.w};
            #pragma unroll
            for (int i = 0; i < 4; ++i)
                #pragma unroll
                for (int jj = 0; jj < 4; ++jj)
                    acc[i][jj] += a[i]*b[jj];
        }
        __syncthreads();
    }
    #pragma unroll
    for (int i = 0; i < 4; ++i) {
        float4 v = make_float4(acc[i][0],acc[i][1],acc[i][2],acc[i][3]);
        *(float4*)&C[(size_t)(bm+tm+i)*N + bn+tn] = v;
    }
}

// fused expand attention: scores -> softmax -> Y, written as fp16 (frozen)
__global__ __launch_bounds__(256) void k_attn2y(const float* __restrict__ Q,
        const float* __restrict__ Kf, const float* __restrict__ Vf,
        unsigned short* __restrict__ Yh) {
    int bl = blockIdx.x; int b = bl / SEQ;
    int t = threadIdx.x;
    __shared__ float q[D_MODEL];
    __shared__ float prt[2][128];
    __shared__ float a[128];
    __shared__ float red[128];
    q[t] = Q[(size_t)bl*D_MODEL + t];
    __syncthreads();
    int s = t & 127, hf = t >> 7;
    const float* kf = Kf + ((size_t)b*NUM_SLOTS + s)*D_MODEL + hf*128;
    float accp = 0.f;
    #pragma unroll 8
    for (int d = 0; d < 128; ++d) accp += q[hf*128 + d]*kf[d];
    prt[hf][s] = accp;
    __syncthreads();
    float v = 0.f;
    if (t < 128) { v = (prt[0][t] + prt[1][t]) * SM_SCALE; red[t] = v; }
    __syncthreads();
    for (int o = 64; o > 0; o >>= 1) { if (t < o) red[t] = fmaxf(red[t], red[t+o]); __syncthreads(); }
    float mx = red[0]; __syncthreads();
    if (t < 128) { float e = expf(v - mx); a[t] = e; red[t] = e; }
    __syncthreads();
    for (int o = 64; o > 0; o >>= 1) { if (t < o) red[t] += red[t+o]; __syncthreads(); }
    float inv = 1.0f / red[0];
    __syncthreads();
    const float* vf = Vf + (size_t)b*NUM_SLOTS*D_MODEL + t;
    float y0 = 0.f, y1 = 0.f, y2 = 0.f, y3 = 0.f;
    #pragma unroll
    for (int s2 = 0; s2 < NUM_SLOTS; s2 += 4) {
        y0 += a[s2+0]*vf[(size_t)(s2+0)*D_MODEL];
        y1 += a[s2+1]*vf[(size_t)(s2+1)*D_MODEL];
        y2 += a[s2+2]*vf[(size_t)(s2+2)*D_MODEL];
        y3 += a[s2+3]*vf[(size_t)(s2+3)*D_MODEL];
    }
    float y = ((y0+y1) + (y2+y3)) * inv;
    Yh[(size_t)bl*D_MODEL + t] = f2h(y);
}

extern "C" void kernel_launch(void* const* d_in, const int* in_sizes, int n_in,
                              void* d_out, int out_size, void* d_ws, size_t ws_size,
                              hipStream_t stream) {
    const int*   ids    = (const int*)d_in[0];
    const int*   amask  = (const int*)d_in[1];
    const float* tok    = (const float*)d_in[2];
    const float* pos    = (const float*)d_in[3];
    const float* Hin    = (const float*)d_in[4];
    const float* Ws     = (const float*)d_in[5];
    const float* Wt     = (const float*)d_in[6];
    const float* Wq_in  = (const float*)d_in[7];
    const float* Wk_sl  = (const float*)d_in[8];
    const float* Wv_in  = (const float*)d_in[9];
    const float* Wq_out = (const float*)d_in[10];
    const float* Wk_fin = (const float*)d_in[11];
    const float* Wv_fin = (const float*)d_in[12];
    const float* Wop    = (const float*)d_in[13];
    const float* lnsc   = (const float*)d_in[14];
    const float* lnbs   = (const float*)d_in[15];
    float* out = (float*)d_out;

    const size_t WF_USH = (size_t)16384 * 16384;     // 512 MiB of ushorts
    unsigned short* WF = (unsigned short*)d_ws;
    float* ws = (float*)(WF + WF_USH);

    float* X    = ws;
    float* Qin  = X    + (size_t)NTOK*D_MODEL;
    float* Vin  = Qin  + (size_t)NTOK*D_MODEL;
    float* Ksl  = Vin  + (size_t)NTOK*D_MODEL;
    float* Asc  = Ksl  + (size_t)NUM_SLOTS*D_MODEL;
    float* csp  = Asc  + (size_t)NTOK*NUM_SLOTS;
    float* Hst  = csp  + (size_t)BATCH*8*NUM_SLOTS;
    float* part = Hst  + (size_t)BATCH*NUM_SLOTS*D_MODEL;
    float* Qout = part + (size_t)IGROUPS*BATCH*NUM_SLOTS*D_MODEL;
    float* Kf   = Qout + (size_t)NTOK*D_MODEL;
    float* Vf   = Kf   + (size_t)BATCH*NUM_SLOTS*D_MODEL;
    float* A2   = Vf   + (size_t)BATCH*NUM_SLOTS*D_MODEL;
    float* Yb   = A2   + (size_t)NTOK*NUM_SLOTS;
    unsigned short* Yh = (unsigned short*)(Yb + (size_t)NTOK*D_MODEL);
    unsigned short* Yl = Yh + (size_t)NTOK*D_MODEL;
    unsigned short* Wf16 = Yl + (size_t)NTOK*D_MODEL;
    unsigned short* Hst16 = Wf16 + (size_t)VOCAB*D_MODEL;

    // front phase: serial small-kernel chain, each overlapped with a slice
    // of the independent weight-conversion blocks
    k_front_a<<<768 + NC_A, 256, 0, stream>>>(ids, tok, pos,
            Wq_in, Wv_in, Wq_out, Qin, Vin, Qout, Ws, Wt, WF);
    k_front_b<<<8008 + NC_B, 256, 0, stream>>>(Hin, Wk_sl, Ksl, Wop, Wf16, Ws, Wt, WF);
    k_front_c<<<NTOK + NC_C, 256, 0, stream>>>(Qin, Ksl, amask, Asc, Ws, Wt, WF);
    k_front_d<<<BATCH*NUM_SLOTS + NC_D, 256, 0, stream>>>(Asc, Vin, Hin, Hst, Hst16, Ws, Wt, WF);

    // bilinear slot-interaction steps
    for (int st = 0; st < N_STEPS; ++st) {
        k_pairs_mfma<<<dim3(NUM_SLOTS, IGROUPS), 256, 0, stream>>>(Hst16, WF, part);
        k_ln<<<BATCH*NUM_SLOTS, 256, 0, stream>>>(Hst, Hst16, part, lnsc + st*D_MODEL, lnbs + st*D_MODEL);
    }
    // expand projections (Kf, Vf fused)
    k_kfvf<<<dim3(BATCH*NUM_SLOTS/64, 4, 2), 256, 0, stream>>>(Hst, Wk_fin, Wv_fin, Kf, Vf);
    // fused expand attention + Y (fp16)
    k_attn2y<<<NTOK, 256, 0, stream>>>(Qout, Kf, Vf, Yh);
    // logits: 1-pass fp16 MFMA with global_load_lds staging
    k_logits<<<dim3(NTOK/128, VOCAB/128), 256, 0, stream>>>(Yh, Wf16, out);
}